// Round 1
// baseline (147.717 us; speedup 1.0000x reference)
//
#include <hip/hip_runtime.h>

// Trilinear interpolation of a [64,64,64,64] fp32 feature volume at 200k points.
// Layout: img[x][y][z][c], coords[p] = (x,y,z) in [0,128); scale = 0.5.
// 16 lanes per point; lane owns 4 channels (float4). Corner gathers are
// 256B contiguous per point -> coalesced; output store coalesced float4.

__device__ __forceinline__ float4 f4mul(float4 a, float s) {
    return make_float4(a.x * s, a.y * s, a.z * s, a.w * s);
}
__device__ __forceinline__ float4 f4fma(float4 a, float s, float4 acc) {
    return make_float4(fmaf(a.x, s, acc.x), fmaf(a.y, s, acc.y),
                       fmaf(a.z, s, acc.z), fmaf(a.w, s, acc.w));
}

__global__ __launch_bounds__(256) void trilerp_kernel(
    const float* __restrict__ img, const float* __restrict__ coords,
    float* __restrict__ out, int n_points)
{
    int tid = blockIdx.x * 256 + threadIdx.x;
    int p = tid >> 4;          // point index
    if (p >= n_points) return;
    int cvec = tid & 15;       // which float4 of the 64-channel vector

    // coords[..., -3] = x, -2 = y, -1 = z ; factor = 128/64 = 2
    float x = coords[3 * p + 0] * 0.5f;
    float y = coords[3 * p + 1] * 0.5f;
    float z = coords[3 * p + 2] * 0.5f;

    float fx1 = floorf(x), fx2 = fminf(ceilf(x), 63.0f);
    float fy1 = floorf(y), fy2 = fminf(ceilf(y), 63.0f);
    float fz1 = floorf(z), fz2 = fminf(ceilf(z), 63.0f);

    float wx = x - fx1, wxc = fx2 - x;   // (x - x1), (x2 - x)
    float wy = y - fy1, wyc = fy2 - y;
    float wz = z - fz1, wzc = fz2 - z;

    int ix1 = (int)fx1, ix2 = (int)fx2;
    int iy1 = (int)fy1, iy2 = (int)fy2;
    int iz1 = (int)fz1, iz2 = (int)fz2;

    const float4* __restrict__ imgv = (const float4*)img;
    // float4 index: (((x<<6)+y)<<6 + z)*16 + cvec   (C=64 floats = 16 float4)
    int bx1 = ix1 << 12, bx2 = ix2 << 12;
    int by1 = iy1 << 6,  by2 = iy2 << 6;

    // z1 plane
    float4 q11 = imgv[((bx1 + by1 + iz1) << 4) + cvec];
    float4 q21 = imgv[((bx2 + by1 + iz1) << 4) + cvec];
    float4 q12 = imgv[((bx1 + by2 + iz1) << 4) + cvec];
    float4 q22 = imgv[((bx2 + by2 + iz1) << 4) + cvec];
    float4 ly1 = f4fma(f4fma(q22, wx, f4mul(q12, wxc)), wy,
                       f4mul(f4fma(q21, wx, f4mul(q11, wxc)), wyc));

    // z2 plane
    q11 = imgv[((bx1 + by1 + iz2) << 4) + cvec];
    q21 = imgv[((bx2 + by1 + iz2) << 4) + cvec];
    q12 = imgv[((bx1 + by2 + iz2) << 4) + cvec];
    q22 = imgv[((bx2 + by2 + iz2) << 4) + cvec];
    float4 ly2 = f4fma(f4fma(q22, wx, f4mul(q12, wxc)), wy,
                       f4mul(f4fma(q21, wx, f4mul(q11, wxc)), wyc));

    float4 res = f4fma(ly2, wz, f4mul(ly1, wzc));
    ((float4*)out)[(p << 4) + cvec] = res;
}

extern "C" void kernel_launch(void* const* d_in, const int* in_sizes, int n_in,
                              void* d_out, int out_size, void* d_ws, size_t ws_size,
                              hipStream_t stream) {
    const float* img    = (const float*)d_in[0];   // [1,64,64,64,64]
    const float* coords = (const float*)d_in[1];   // [1,N,3]
    float* out = (float*)d_out;                    // [1,N,64]
    int n_points = in_sizes[1] / 3;

    int threads = n_points * 16;
    int grid = (threads + 255) / 256;
    trilerp_kernel<<<grid, 256, 0, stream>>>(img, coords, out, n_points);
}